// Round 3
// baseline (725.525 us; speedup 1.0000x reference)
//
#include <hip/hip_runtime.h>
#include <hip/hip_bf16.h>
#include <math.h>

#define NBINS 10
#define NVALS 21          // 0:bce, 1..10:counts, 11..20:sum((p-t)*w)
#define THREADS 256
#define PAD_PAIRS 11      // 10 (sumd,cnt) pairs + 1 pad pair -> 22-word stride

// Per-element work. LDS slot `my` holds 10 float2 {sumd, cnt} pairs.
// ds_add_f32 (non-returning LDS atomic) -> no RAW dependence chain:
// the thread never waits for the histogram update to complete.
__device__ __forceinline__ void proc(float x0, float t0, float& bce_acc,
                                     float* __restrict__ my) {
  bool valid = (x0 == x0) && (t0 == t0);
  float x = valid ? x0 : 0.f;
  float t = valid ? __builtin_amdgcn_fmed3f(t0, 0.f, 1.f) : 0.f;
  float w = valid ? 1.f : 0.f;

  // softplus(-x) = max(-x,0) + log(1 + exp(-|x|))
  float e = __expf(-fabsf(x));                 // v_mul(log2e) + v_exp
  float L = 1.f + e;
  float sp = __logf(L) + fmaxf(-x, 0.f);
  float coef = __builtin_fmaf(79.f, t, 1.f);   // 80t + (1-t)
  float ax = __builtin_fmaf(-t, x, x);         // (1-t)*x
  float bce = __builtin_fmaf(coef, sp, ax);
  bce_acc = __builtin_fmaf(bce, w, bce_acc);

  // sigmoid via the already-computed e, L
  float r = __builtin_amdgcn_rcpf(L);
  float p = (x >= 0.f) ? r : e * r;
  int bin = (int)(p * 10.f);
  bin = bin > 9 ? 9 : bin;
  float d = (p - t) * w;

  atomicAdd(&my[bin * 2], d);       // ds_add_f32, fire-and-forget
  atomicAdd(&my[bin * 2 + 1], w);   // ds_add_f32
}

__global__ __launch_bounds__(THREADS) void dl_partial(
    const float* __restrict__ pred, const float* __restrict__ targ,
    long long n, float* __restrict__ ws, int grid) {
  __shared__ float hist[THREADS * PAD_PAIRS * 2];
  __shared__ float red[4][NVALS];

  const int tid = threadIdx.x;
  float* my = hist + tid * (PAD_PAIRS * 2);   // 88B stride
#pragma unroll
  for (int b = 0; b < NBINS * 2; ++b) my[b] = 0.f;

  const long long gid = (long long)blockIdx.x * THREADS + tid;
  const long long stride = (long long)grid * THREADS;
  const long long nvec = n >> 2;

  float bce_acc = 0.f;
  const float4* p4 = (const float4*)pred;
  const float4* t4 = (const float4*)targ;
  for (long long i = gid; i < nvec; i += stride) {
    float4 xv = p4[i];
    float4 tv = t4[i];
    proc(xv.x, tv.x, bce_acc, my);
    proc(xv.y, tv.y, bce_acc, my);
    proc(xv.z, tv.z, bce_acc, my);
    proc(xv.w, tv.w, bce_acc, my);
  }
  long long ti = (nvec << 2) + gid;
  if (ti < n) proc(pred[ti], targ[ti], bce_acc, my);

  __syncthreads();   // drain LDS atomics (same-wave ordering is enough, but cheap)

  // gather own slots, then block-reduce
  float vals[NVALS];
  vals[0] = bce_acc;
#pragma unroll
  for (int b = 0; b < NBINS; ++b) {
    vals[1 + b] = my[b * 2 + 1];   // count
    vals[11 + b] = my[b * 2];      // sum (p-t)*w
  }
#pragma unroll
  for (int v = 0; v < NVALS; ++v) {
#pragma unroll
    for (int off = 32; off; off >>= 1) vals[v] += __shfl_xor(vals[v], off, 64);
  }
  const int lane = tid & 63;
  const int wave = tid >> 6;
  if (lane == 0) {
#pragma unroll
    for (int v = 0; v < NVALS; ++v) red[wave][v] = vals[v];
  }
  __syncthreads();
  if (tid < NVALS) {
    float s = red[0][tid] + red[1][tid] + red[2][tid] + red[3][tid];
    ws[(long long)tid * grid + blockIdx.x] = s;  // SoA for coalesced final pass
  }
}

__global__ __launch_bounds__(THREADS) void dl_final(
    const float* __restrict__ ws, float* __restrict__ out, int grid) {
  __shared__ double totals[NVALS];
  __shared__ double wred[4];
  const int tid = threadIdx.x;
  for (int r = 0; r < NVALS; ++r) {
    double psum = 0.0;
    for (int i = tid; i < grid; i += THREADS)
      psum += (double)ws[(long long)r * grid + i];
#pragma unroll
    for (int off = 32; off; off >>= 1) psum += __shfl_xor(psum, off, 64);
    if ((tid & 63) == 0) wred[tid >> 6] = psum;
    __syncthreads();
    if (tid == 0) totals[r] = wred[0] + wred[1] + wred[2] + wred[3];
    __syncthreads();
  }
  if (tid == 0) {
    double bce = totals[0];
    double nv = 0.0;
    for (int b = 0; b < NBINS; ++b) nv += totals[1 + b];  // n_valid = sum counts
    double dist = 0.0;
    for (int b = 0; b < NBINS; ++b) {
      double c = totals[1 + b], sd = totals[11 + b];
      double safe = c > 1.0 ? c : 1.0;
      if (c > 10.0) dist += fabs(sd) / safe;
    }
    out[0] = (float)(bce / nv + dist / (double)NBINS * 0.2);
  }
}

extern "C" void kernel_launch(void* const* d_in, const int* in_sizes, int n_in,
                              void* d_out, int out_size, void* d_ws, size_t ws_size,
                              hipStream_t stream) {
  const float* pred = (const float*)d_in[0];
  const float* targ = (const float*)d_in[1];
  const long long n = (long long)in_sizes[0];
  float* out = (float*)d_out;
  float* ws = (float*)d_ws;

  int grid = 1792;  // 7 blocks/CU x 256 CUs (LDS-capped: 23 KB/block)
  while (grid > 64 && (size_t)NVALS * grid * sizeof(float) > ws_size) grid >>= 1;

  dl_partial<<<grid, THREADS, 0, stream>>>(pred, targ, n, ws, grid);
  dl_final<<<1, THREADS, 0, stream>>>(ws, out, grid);
}

// Round 4
// 184.184 us; speedup vs baseline: 3.9391x; 3.9391x over previous
//
#include <hip/hip_runtime.h>
#include <hip/hip_bf16.h>
#include <math.h>

#define NBINS 10
#define NVALS 21          // 0:bce, 1..10:counts, 11..20:sum((p-t)*w)
#define THREADS 256
#define HSTRIDE 11        // words/thread; gcd(11,32)=1 -> conflict-free bases

// Per-element work.
//  - bce accumulated in VGPR
//  - sum((p-t)*w) per bin: single b32 LDS RMW into private slot
//  - counts: ballot+popcount into wave-uniform scalars (SALU, free vs VALU)
__device__ __forceinline__ void proc(float x0, float t0, float& bce_acc,
                                     unsigned* cnt, float* __restrict__ my) {
  bool valid = (x0 == x0) && (t0 == t0);
  float x = valid ? x0 : 0.f;
  float t = valid ? __builtin_amdgcn_fmed3f(t0, 0.f, 1.f) : 0.f;
  float w = valid ? 1.f : 0.f;

  // sigmoid pieces; softplus(-x) = -ln(sigmoid(x)) reuses them
  float e = __expf(-fabsf(x));                 // exp(-|x|)
  float L = 1.f + e;
  float r = __builtin_amdgcn_rcpf(L);
  float p = (x >= 0.f) ? r : e * r;            // sigmoid(x)
  float lnp = __logf(p);                       // = -softplus(-x)
  float coef = __builtin_fmaf(79.f, t, 1.f);   // 80t + (1-t)
  float omtx = __builtin_fmaf(-t, x, x);       // (1-t)*x
  float b = __builtin_fmaf(coef, -lnp, omtx);  // bce
  bce_acc = __builtin_fmaf(b, w, bce_acc);

  int bin = (int)(p * 10.f);
  bin = bin > 9 ? 9 : bin;
  float d = (p - t) * w;
  my[bin] += d;                // ds_read_b32 + v_add + ds_write_b32 (d=0 if invalid)

  int binv = valid ? bin : 255;                // invalid hits no count bin
#pragma unroll
  for (int bb = 0; bb < NBINS; ++bb)
    cnt[bb] += (unsigned)__popcll(__ballot(binv == bb));  // s_bcnt1 + s_add
}

__global__ __launch_bounds__(THREADS, 8) void dl_partial(
    const float* __restrict__ pred, const float* __restrict__ targ,
    long long n, float* __restrict__ ws, int grid) {
  __shared__ float hist[THREADS * HSTRIDE];
  __shared__ float red[4][NVALS];

  const int tid = threadIdx.x;
  float* my = hist + tid * HSTRIDE;
#pragma unroll
  for (int b = 0; b < NBINS; ++b) my[b] = 0.f;

  const long long gid = (long long)blockIdx.x * THREADS + tid;
  const long long stride = (long long)grid * THREADS;
  const long long nvec = n >> 2;

  float bce_acc = 0.f;
  unsigned cnt[NBINS];
#pragma unroll
  for (int b = 0; b < NBINS; ++b) cnt[b] = 0u;

  const float4* p4 = (const float4*)pred;
  const float4* t4 = (const float4*)targ;

  // 1-deep software prefetch: next iteration's loads issue before this
  // iteration's LDS RMW chain.
  long long i = gid;
  float4 xv = make_float4(0.f, 0.f, 0.f, 0.f), tv = xv;
  if (i < nvec) { xv = p4[i]; tv = t4[i]; }
  while (i < nvec) {
    const long long nx = i + stride;
    float4 xn = make_float4(0.f, 0.f, 0.f, 0.f), tn = xn;
    if (nx < nvec) { xn = p4[nx]; tn = t4[nx]; }
    proc(xv.x, tv.x, bce_acc, cnt, my);
    proc(xv.y, tv.y, bce_acc, cnt, my);
    proc(xv.z, tv.z, bce_acc, cnt, my);
    proc(xv.w, tv.w, bce_acc, cnt, my);
    xv = xn; tv = tn; i = nx;
  }
  long long ti = (nvec << 2) + gid;
  if (ti < n) proc(pred[ti], targ[ti], bce_acc, cnt, my);

  // gather own LDS slots (same-wave program order; no barrier needed)
  float vals[NVALS];
  const int lane = tid & 63;
  vals[0] = bce_acc;
#pragma unroll
  for (int b = 0; b < NBINS; ++b) {
    vals[1 + b] = (lane == 0) ? (float)cnt[b] : 0.f;  // wave-uniform counts
    vals[11 + b] = my[b];
  }
#pragma unroll
  for (int v = 0; v < NVALS; ++v) {
#pragma unroll
    for (int off = 32; off; off >>= 1) vals[v] += __shfl_xor(vals[v], off, 64);
  }
  const int wave = tid >> 6;
  if (lane == 0) {
#pragma unroll
    for (int v = 0; v < NVALS; ++v) red[wave][v] = vals[v];
  }
  __syncthreads();
  if (tid < NVALS) {
    float s = red[0][tid] + red[1][tid] + red[2][tid] + red[3][tid];
    ws[(long long)tid * grid + blockIdx.x] = s;  // SoA for coalesced final pass
  }
}

__global__ __launch_bounds__(THREADS) void dl_final(
    const float* __restrict__ ws, float* __restrict__ out, int grid) {
  __shared__ double totals[NVALS];
  __shared__ double wred[4];
  const int tid = threadIdx.x;
  for (int r = 0; r < NVALS; ++r) {
    double psum = 0.0;
    for (int i = tid; i < grid; i += THREADS)
      psum += (double)ws[(long long)r * grid + i];
#pragma unroll
    for (int off = 32; off; off >>= 1) psum += __shfl_xor(psum, off, 64);
    if ((tid & 63) == 0) wred[tid >> 6] = psum;
    __syncthreads();
    if (tid == 0) totals[r] = wred[0] + wred[1] + wred[2] + wred[3];
    __syncthreads();
  }
  if (tid == 0) {
    double bce = totals[0];
    double nv = 0.0;
    for (int b = 0; b < NBINS; ++b) nv += totals[1 + b];  // n_valid = sum counts
    double dist = 0.0;
    for (int b = 0; b < NBINS; ++b) {
      double c = totals[1 + b], sd = totals[11 + b];
      double safe = c > 1.0 ? c : 1.0;
      if (c > 10.0) dist += fabs(sd) / safe;
    }
    out[0] = (float)(bce / nv + dist / (double)NBINS * 0.2);
  }
}

extern "C" void kernel_launch(void* const* d_in, const int* in_sizes, int n_in,
                              void* d_out, int out_size, void* d_ws, size_t ws_size,
                              hipStream_t stream) {
  const float* pred = (const float*)d_in[0];
  const float* targ = (const float*)d_in[1];
  const long long n = (long long)in_sizes[0];
  float* out = (float*)d_out;
  float* ws = (float*)d_ws;

  int grid = 2048;  // 8 blocks/CU x 256 CUs; 11.5 KB LDS -> wave-limited, 100% occ
  while (grid > 64 && (size_t)NVALS * grid * sizeof(float) > ws_size) grid >>= 1;

  dl_partial<<<grid, THREADS, 0, stream>>>(pred, targ, n, ws, grid);
  dl_final<<<1, THREADS, 0, stream>>>(ws, out, grid);
}

// Round 5
// 147.999 us; speedup vs baseline: 4.9022x; 1.2445x over previous
//
#include <hip/hip_runtime.h>
#include <hip/hip_bf16.h>
#include <math.h>

#define NBINS 10
#define NVALS 21          // 0:bce, 1..10:counts, 11..20:sum((p-t)*w)
#define THREADS 256
#define TSTRIDE 22        // words/thread: 2 replica histograms x 11 words

// Per-element work.
//  - bce accumulated in VGPR
//  - sum((p-t)) per bin: single b32 LDS RMW into a per-thread replica slot
//    (caller alternates replicas -> dependence chains 2 elements apart)
//  - counts: 6-bit packed fields in one u64 VGPR (~5 VALU), flushed periodically
__device__ __forceinline__ void proc(float x0, float t0, float& bce_acc,
                                     unsigned long long& c6,
                                     float* __restrict__ myrep) {
  bool valid = (x0 == x0) && (t0 == t0);            // -> v_cmp_o
  float x = valid ? x0 : 0.f;
  float t = valid ? __builtin_amdgcn_fmed3f(t0, 0.f, 1.f) : 0.f;

  // sigmoid pieces; softplus(-x) = -ln(sigmoid(x)) reuses them
  float e = __expf(-fabsf(x));                      // exp(-|x|)
  float L = 1.f + e;
  float r = __builtin_amdgcn_rcpf(L);
  float p = (x >= 0.f) ? r : e * r;                 // sigmoid(x)
  float l2p = __log2f(p);                           // log2(sigmoid)
  // bce = (1-t)x + (80t+1-t)*(-ln p) = fma(coef2, log2(p), (1-t)x)
  const float NLN2 = -0.6931471805599453f;
  float coef2 = __builtin_fmaf(79.f * NLN2, t, NLN2);  // -(80t+1-t)ln2
  float omtx = __builtin_fmaf(-t, x, x);               // (1-t)*x
  float b = __builtin_fmaf(coef2, l2p, omtx);
  bce_acc += valid ? b : 0.f;

  int bin = (int)(p * 10.f);
  bin = bin > 9 ? 9 : bin;
  float d = valid ? (p - t) : 0.f;
  myrep[bin] += d;                 // ds_read_b32 + v_add + ds_write_b32

  unsigned inc = valid ? 1u : 0u;
  c6 += (unsigned long long)inc << (unsigned)(bin * 6);
}

__global__ __launch_bounds__(THREADS, 7) void dl_partial(
    const float* __restrict__ pred, const float* __restrict__ targ,
    long long n, float* __restrict__ ws, int grid) {
  __shared__ float hist[THREADS * TSTRIDE];   // 22528 B -> 7 blocks/CU

  const int tid = threadIdx.x;
  float* my0 = hist + tid * TSTRIDE;          // replica 0: words 0..10
  float* my1 = my0 + 11;                      // replica 1: words 11..21
#pragma unroll
  for (int b = 0; b < TSTRIDE; ++b) my0[b] = 0.f;

  const long long gid = (long long)blockIdx.x * THREADS + tid;
  const long long stride = (long long)grid * THREADS;
  const long long nvec = n >> 2;

  float bce_acc = 0.f;
  unsigned long long c6 = 0ull;    // 10 x 6-bit packed counts
  unsigned cnt[NBINS];
#pragma unroll
  for (int b = 0; b < NBINS; ++b) cnt[b] = 0u;

  const float4* p4 = (const float4*)pred;
  const float4* t4 = (const float4*)targ;

  // 1-deep software prefetch; flush packed counts every 8 iters (32 elems < 63 cap)
  long long i = gid;
  unsigned it = 0;
  float4 xv = make_float4(0.f, 0.f, 0.f, 0.f), tv = xv;
  if (i < nvec) { xv = p4[i]; tv = t4[i]; }
  while (i < nvec) {
    const long long nx = i + stride;
    float4 xn = make_float4(0.f, 0.f, 0.f, 0.f), tn = xn;
    if (nx < nvec) { xn = p4[nx]; tn = t4[nx]; }
    proc(xv.x, tv.x, bce_acc, c6, my0);
    proc(xv.y, tv.y, bce_acc, c6, my1);
    proc(xv.z, tv.z, bce_acc, c6, my0);
    proc(xv.w, tv.w, bce_acc, c6, my1);
    if ((++it & 7u) == 0u) {
#pragma unroll
      for (int b = 0; b < NBINS; ++b)
        cnt[b] += (unsigned)((c6 >> (6 * b)) & 63ull);
      c6 = 0ull;
    }
    xv = xn; tv = tn; i = nx;
  }
  long long ti = (nvec << 2) + gid;
  if (ti < n) proc(pred[ti], targ[ti], bce_acc, c6, my0);
#pragma unroll
  for (int b = 0; b < NBINS; ++b)
    cnt[b] += (unsigned)((c6 >> (6 * b)) & 63ull);

  // gather own LDS slots (same-wave program order; no barrier needed)
  float vals[NVALS];
  vals[0] = bce_acc;
#pragma unroll
  for (int b = 0; b < NBINS; ++b) {
    vals[1 + b] = (float)cnt[b];
    vals[11 + b] = my0[b] + my1[b];
  }
#pragma unroll
  for (int v = 0; v < NVALS; ++v) {
#pragma unroll
    for (int off = 32; off; off >>= 1) vals[v] += __shfl_xor(vals[v], off, 64);
  }
  // block reduction reusing hist as scratch
  const int lane = tid & 63;
  const int wave = tid >> 6;
  __syncthreads();                 // everyone done reading their slots
  if (lane == 0) {
#pragma unroll
    for (int v = 0; v < NVALS; ++v) hist[wave * NVALS + v] = vals[v];
  }
  __syncthreads();
  if (tid < NVALS) {
    float s = hist[tid] + hist[NVALS + tid] + hist[2 * NVALS + tid] +
              hist[3 * NVALS + tid];
    ws[(long long)tid * grid + blockIdx.x] = s;  // SoA for coalesced final pass
  }
}

__global__ __launch_bounds__(THREADS) void dl_final(
    const float* __restrict__ ws, float* __restrict__ out, int grid) {
  __shared__ double totals[NVALS];
  __shared__ double wred[4];
  const int tid = threadIdx.x;
  for (int r = 0; r < NVALS; ++r) {
    double psum = 0.0;
    for (int i = tid; i < grid; i += THREADS)
      psum += (double)ws[(long long)r * grid + i];
#pragma unroll
    for (int off = 32; off; off >>= 1) psum += __shfl_xor(psum, off, 64);
    if ((tid & 63) == 0) wred[tid >> 6] = psum;
    __syncthreads();
    if (tid == 0) totals[r] = wred[0] + wred[1] + wred[2] + wred[3];
    __syncthreads();
  }
  if (tid == 0) {
    double bce = totals[0];
    double nv = 0.0;
    for (int b = 0; b < NBINS; ++b) nv += totals[1 + b];  // n_valid = sum counts
    double dist = 0.0;
    for (int b = 0; b < NBINS; ++b) {
      double c = totals[1 + b], sd = totals[11 + b];
      double safe = c > 1.0 ? c : 1.0;
      if (c > 10.0) dist += fabs(sd) / safe;
    }
    out[0] = (float)(bce / nv + dist / (double)NBINS * 0.2);
  }
}

extern "C" void kernel_launch(void* const* d_in, const int* in_sizes, int n_in,
                              void* d_out, int out_size, void* d_ws, size_t ws_size,
                              hipStream_t stream) {
  const float* pred = (const float*)d_in[0];
  const float* targ = (const float*)d_in[1];
  const long long n = (long long)in_sizes[0];
  float* out = (float*)d_out;
  float* ws = (float*)d_ws;

  int grid = 1792;  // 7 blocks/CU x 256 CUs (LDS-capped at 7 -> 87.5% occ)
  while (grid > 64 && (size_t)NVALS * grid * sizeof(float) > ws_size) grid >>= 1;

  dl_partial<<<grid, THREADS, 0, stream>>>(pred, targ, n, ws, grid);
  dl_final<<<1, THREADS, 0, stream>>>(ws, out, grid);
}